// Round 10
// baseline (243.654 us; speedup 1.0000x reference)
//
#include <hip/hip_runtime.h>
#include <hip/hip_bf16.h>
#include <hip/hip_fp16.h>
#include <math.h>

#define NFEAT 128
#define NCLS  64
#define WSTR  132           // W LDS row stride in halves
#define NBLK  256           // fixed grid for hist/scatter replay passes
#define RQ8   8             // uint4 per fp8 row (128 B)

// ---------- fp8 e4m3 pack/unpack ----------

typedef float f32x2 __attribute__((ext_vector_type(2)));

#if __has_builtin(__builtin_amdgcn_cvt_pk_f32_fp8) && __has_builtin(__builtin_amdgcn_cvt_pk_fp8_f32)
#define HW_FP8 1
#endif

#ifndef HW_FP8
__device__ __forceinline__ float dec1(unsigned int b) {
    unsigned int s = b & 0x80, e = (b >> 3) & 15, m = b & 7;
    float v = e ? ldexpf((float)(8 + (int)m), (int)e - 10) : ldexpf((float)m, -9);
    return s ? -v : v;
}
__device__ __forceinline__ unsigned int enc1(float f) {
    unsigned int u = __float_as_uint(f);
    unsigned int s = (u >> 24) & 0x80;
    float a = fabsf(f);
    if (a > 448.f) return s | 0x7e;
    if (a < 0x1p-10f) return s;
    int eb = (int)((u >> 23) & 0xff) - 127;
    int e = eb < -6 ? -6 : eb;
    float step = ldexpf(1.f, e - 3);
    float q = rintf(a / step) * step;
    u = __float_as_uint(q);
    eb = (int)((u >> 23) & 0xff) - 127;
    unsigned int code;
    if (eb < -6) code = (unsigned int)(q * 512.f);
    else         code = ((unsigned int)(eb + 7) << 3) | ((u >> 20) & 7);
    return s | code;
}
#endif

__device__ __forceinline__ void unpack4(float* o, unsigned int u) {
#ifdef HW_FP8
    f32x2 lo = __builtin_amdgcn_cvt_pk_f32_fp8((int)u, false);
    f32x2 hi = __builtin_amdgcn_cvt_pk_f32_fp8((int)u, true);
    o[0] = lo.x; o[1] = lo.y; o[2] = hi.x; o[3] = hi.y;
#else
    o[0] = dec1(u & 255); o[1] = dec1((u >> 8) & 255);
    o[2] = dec1((u >> 16) & 255); o[3] = dec1(u >> 24);
#endif
}
__device__ __forceinline__ unsigned int pack4(float a, float b, float c, float d) {
#ifdef HW_FP8
    int w = 0;
    w = __builtin_amdgcn_cvt_pk_fp8_f32(a, b, w, false);
    w = __builtin_amdgcn_cvt_pk_fp8_f32(c, d, w, true);
    return (unsigned int)w;
#else
    return enc1(a) | (enc1(b) << 8) | (enc1(c) << 16) | (enc1(d) << 24);
#endif
}

__device__ __forceinline__ void accum_f8(float acc[16], uint4 v) {
    unsigned int u[4] = {v.x, v.y, v.z, v.w};
    #pragma unroll
    for (int t = 0; t < 4; ++t) {
        float f[4];
        unpack4(f, u[t]);
        acc[4 * t + 0] += f[0]; acc[4 * t + 1] += f[1];
        acc[4 * t + 2] += f[2]; acc[4 * t + 3] += f[3];
    }
}

typedef _Float16 h2v __attribute__((ext_vector_type(2)));

__device__ __forceinline__ float dot2acc(unsigned int hv, unsigned int wv, float c) {
#if __has_builtin(__builtin_amdgcn_fdot2)
    union { unsigned int u; h2v v; } a, bq; a.u = hv; bq.u = wv;
    return __builtin_amdgcn_fdot2(a.v, bq.v, c, false);
#else
    union { unsigned int u; __half2 h; } a, bq; a.u = hv; bq.u = wv;
    float2 fa = __half22float2(a.h), fb = __half22float2(bq.h);
    return fmaf(fa.x, fb.x, fmaf(fa.y, fb.y, c));
#endif
}

// ---------- build pass 1: per-node count + coarse bucket histogram ----------
__global__ __launch_bounds__(256) void histcount_kernel(const int* __restrict__ dst,
                                                        int* __restrict__ cnt,
                                                        int* __restrict__ h,
                                                        int E4, int E, int nbuck) {
    __shared__ int lh[256];
    const int tid = threadIdx.x;
    lh[tid] = 0;
    __syncthreads();
    for (int idx = blockIdx.x * 256 + tid; idx < E4; idx += NBLK * 256) {
        int base = idx * 4;
        if (base + 3 < E) {
            int4 d = ((const int4*)dst)[idx];
            atomicAdd(&cnt[d.x], 1); atomicAdd(&lh[d.x >> 8], 1);
            atomicAdd(&cnt[d.y], 1); atomicAdd(&lh[d.y >> 8], 1);
            atomicAdd(&cnt[d.z], 1); atomicAdd(&lh[d.z >> 8], 1);
            atomicAdd(&cnt[d.w], 1); atomicAdd(&lh[d.w >> 8], 1);
        } else {
            for (int e = base; e < E; ++e) {
                int d = dst[e];
                atomicAdd(&cnt[d], 1); atomicAdd(&lh[d >> 8], 1);
            }
        }
    }
    __syncthreads();
    if (tid < nbuck) h[blockIdx.x * 256 + tid] = lh[tid];
}

__global__ __launch_bounds__(256) void bucket_colscan_kernel(int* __restrict__ h,
                                                             int* __restrict__ btot) {
    __shared__ int lds[256];
    const int tid = threadIdx.x;
    const int B = blockIdx.x;
    int v = h[tid * 256 + B];
    lds[tid] = v;
    __syncthreads();
    for (int off = 1; off < 256; off <<= 1) {
        int t = (tid >= off) ? lds[tid - off] : 0;
        __syncthreads();
        lds[tid] += t;
        __syncthreads();
    }
    h[tid * 256 + B] = lds[tid] - v;
    if (tid == 255) btot[B] = lds[255];
}

__global__ __launch_bounds__(256) void bucket_scan_kernel(const int* __restrict__ btot,
                                                          int* __restrict__ bbase, int nbuck) {
    __shared__ int lds[256];
    const int tid = threadIdx.x;
    int v = (tid < nbuck) ? btot[tid] : 0;
    lds[tid] = v;
    __syncthreads();
    for (int off = 1; off < 256; off <<= 1) {
        int t = (tid >= off) ? lds[tid - off] : 0;
        __syncthreads();
        lds[tid] += t;
        __syncthreads();
    }
    if (tid < nbuck) bbase[tid] = lds[tid] - v;
    if (tid == nbuck - 1) bbase[nbuck] = lds[tid];
}

__global__ __launch_bounds__(256) void bucket_scatter_kernel(const int* __restrict__ src,
                                                             const int* __restrict__ dst,
                                                             const int* __restrict__ h,
                                                             const int* __restrict__ bbase,
                                                             int* __restrict__ bsrc,
                                                             int* __restrict__ bdst,
                                                             int E4, int E, int nbuck) {
    __shared__ int cur[256];
    const int tid = threadIdx.x;
    if (tid < nbuck) cur[tid] = bbase[tid] + h[blockIdx.x * 256 + tid];
    __syncthreads();
    for (int idx = blockIdx.x * 256 + tid; idx < E4; idx += NBLK * 256) {
        int base = idx * 4;
        if (base + 3 < E) {
            int4 s = ((const int4*)src)[idx];
            int4 d = ((const int4*)dst)[idx];
            int p;
            p = atomicAdd(&cur[d.x >> 8], 1); bsrc[p] = s.x; bdst[p] = d.x;
            p = atomicAdd(&cur[d.y >> 8], 1); bsrc[p] = s.y; bdst[p] = d.y;
            p = atomicAdd(&cur[d.z >> 8], 1); bsrc[p] = s.z; bdst[p] = d.z;
            p = atomicAdd(&cur[d.w >> 8], 1); bsrc[p] = s.w; bdst[p] = d.w;
        } else {
            for (int e = base; e < E; ++e) {
                int p = atomicAdd(&cur[dst[e] >> 8], 1);
                bsrc[p] = src[e]; bdst[p] = dst[e];
            }
        }
    }
}

__global__ __launch_bounds__(256) void drain_kernel(const int* __restrict__ bsrc,
                                                    const int* __restrict__ bdst,
                                                    const int* __restrict__ bbase,
                                                    int* __restrict__ cursor,
                                                    int* __restrict__ csr) {
    const int B = blockIdx.x;
    const int s0 = bbase[B], s1 = bbase[B + 1];
    for (int e = s0 + threadIdx.x; e < s1; e += 256) {
        int sj = bsrc[e], dj = bdst[e];
        int pos = atomicAdd(&cursor[dj], 1);
        csr[pos] = sj;
    }
}

// ---------- scans over counts padded to multiple of 8 ----------

__global__ void scan_local(const int* __restrict__ cnt, int* __restrict__ row_ptr,
                           int* __restrict__ bsums, int n) {
    __shared__ int lds[256];
    const int tid = threadIdx.x;
    int i = blockIdx.x * 256 + tid;
    int v = (i < n) ? ((cnt[i] + 7) & ~7) : 0;
    lds[tid] = v;
    __syncthreads();
    for (int off = 1; off < 256; off <<= 1) {
        int t = (tid >= off) ? lds[tid - off] : 0;
        __syncthreads();
        lds[tid] += t;
        __syncthreads();
    }
    if (i < n) row_ptr[i + 1] = lds[tid];
    if (tid == 255) bsums[blockIdx.x] = lds[255];
}

__global__ void scan_finalize(const int* __restrict__ cnt, const int* __restrict__ bsums,
                              int* __restrict__ row_ptr, int* __restrict__ cursor,
                              float* __restrict__ dinv, int n) {
    __shared__ int wsum[4];
    const int tid = threadIdx.x;
    int v = (tid < blockIdx.x) ? bsums[tid] : 0;
    for (int o = 32; o > 0; o >>= 1) v += __shfl_xor(v, o);
    if ((tid & 63) == 0) wsum[tid >> 6] = v;
    __syncthreads();
    int off = wsum[0] + wsum[1] + wsum[2] + wsum[3];

    int i = blockIdx.x * 256 + tid;
    if (i < n) {
        int incl = row_ptr[i + 1] + off;
        row_ptr[i + 1] = incl;
        int c = cnt[i];
        int cp = (c + 7) & ~7;
        cursor[i] = incl - cp;                     // row start; pads land at row end
        dinv[i] = rsqrtf((float)c + 1.0f);         // +1 self-loop
        if (i == 0) row_ptr[0] = 0;
    }
}

__global__ void fill_kernel(int* __restrict__ csr, int val, int total4) {
    int idx = blockIdx.x * blockDim.x + threadIdx.x;
    if (idx < total4) {
        int4 v = {val, val, val, val};
        ((int4*)csr)[idx] = v;
    }
}

// ---------- prep: xq[j] = fp8(dinv[j]*x[j]); zero dummy row N of xq & y1q ----------
__global__ void prep_kernel(const float* __restrict__ x, const float* __restrict__ dinv,
                            uint4* __restrict__ xq, uint4* __restrict__ y1q, int N) {
    int idx = blockIdx.x * blockDim.x + threadIdx.x;   // one uint4 (16 fp8) per thread
    int total = N * RQ8;
    if (idx < total) {
        float d = dinv[idx >> 3];
        const float4* X4 = (const float4*)x;
        uint4 r;
        unsigned int* rp = (unsigned int*)&r;
        #pragma unroll
        for (int t = 0; t < 4; ++t) {
            float4 v = X4[(size_t)idx * 4 + t];
            rp[t] = pack4(d * v.x, d * v.y, d * v.z, d * v.w);
        }
        xq[idx] = r;
    } else if (idx < total + RQ8) {
        xq[idx]  = uint4{0, 0, 0, 0};
        y1q[idx] = uint4{0, 0, 0, 0};
    }
}

// ---------- fp8 gather core: 8 edges per load instr, rows padded to x8 ----------
__device__ __forceinline__ void gather_row8(float acc[16], const uint4* __restrict__ X,
                                            const int* __restrict__ csr,
                                            int ks, int ke, int e, int q) {
    int k = ks;
    int ja, jb;
    bool have = (k + 16 <= ke);
    if (have) { ja = csr[k + e]; jb = csr[k + 8 + e]; }
    while (have) {
        uint4 va = X[(size_t)ja * RQ8 + q];
        uint4 vb = X[(size_t)jb * RQ8 + q];
        k += 16;
        have = (k + 16 <= ke);
        if (have) { ja = csr[k + e]; jb = csr[k + 8 + e]; }   // prefetch indices
        accum_f8(acc, va);
        accum_f8(acc, vb);
    }
    if (k < ke) {                                 // exactly 8 padded edges
        int j = csr[k + e];
        accum_f8(acc, X[(size_t)j * RQ8 + q]);
    }
}

// ---------- generic hop over fp8 rows ----------
// SQUARE: scale dinv^2 (hop1) vs dinv (hop2). OUT16: write fp16 row (for cls).
template <int SQUARE, int OUT16>
__global__ __launch_bounds__(256) void hop_kernel(const uint4* __restrict__ Xq,
                                                  const float* __restrict__ dinv,
                                                  const int* __restrict__ row_ptr,
                                                  const int* __restrict__ csr,
                                                  void* __restrict__ outv, int N) {
    const int tid = threadIdx.x;
    const int w = tid >> 6, lane = tid & 63;
    const int i = blockIdx.x * 4 + w;
    if (i >= N) return;                           // wave-uniform; no barriers
    const int e = lane >> 3;                      // edge slot 0..7
    const int q = lane & 7;                       // 16 B chunk of 128 B row

    float acc[16];
    #pragma unroll
    for (int t = 0; t < 16; ++t) acc[t] = 0.f;

    int ks = row_ptr[i], ke = row_ptr[i + 1];
    gather_row8(acc, Xq, csr, ks, ke, e, q);
    if (e == 0) accum_f8(acc, Xq[(size_t)i * RQ8 + q]);   // self term

    #pragma unroll
    for (int t = 0; t < 16; ++t) {
        acc[t] += __shfl_xor(acc[t], 8);
        acc[t] += __shfl_xor(acc[t], 16);
        acc[t] += __shfl_xor(acc[t], 32);
    }

    if (e == 0) {
        float di = dinv[i];
        float s = SQUARE ? di * di : di;
        if (OUT16) {
            __half* oh = (__half*)outv;
            union { uint4 u; __half2 h[4]; } r0, r1;
            #pragma unroll
            for (int t = 0; t < 4; ++t) {
                r0.h[t] = __floats2half2_rn(s * acc[2 * t], s * acc[2 * t + 1]);
                r1.h[t] = __floats2half2_rn(s * acc[8 + 2 * t], s * acc[9 + 2 * t]);
            }
            ((uint4*)oh)[(size_t)i * 16 + q * 2]     = r0.u;
            ((uint4*)oh)[(size_t)i * 16 + q * 2 + 1] = r1.u;
        } else {
            uint4 r;
            unsigned int* rp = (unsigned int*)&r;
            #pragma unroll
            for (int t = 0; t < 4; ++t)
                rp[t] = pack4(s * acc[4 * t], s * acc[4 * t + 1],
                              s * acc[4 * t + 2], s * acc[4 * t + 3]);
            ((uint4*)outv)[(size_t)i * RQ8 + q] = r;
        }
    }
}

// ---------- classifier: logits = x2 @ W^T + b, log_softmax ----------
__global__ __launch_bounds__(512) void cls_kernel(const __half* __restrict__ x2h,
                                                  const float* __restrict__ W,
                                                  const float* __restrict__ b,
                                                  float* __restrict__ out, int N) {
    __shared__ __half Wl[NCLS * WSTR];
    __shared__ __align__(16) __half HT[64][NFEAT];

    const int tid = threadIdx.x;
    const int w = tid >> 6, lane = tid & 63;

    for (int e = tid; e < NCLS * NFEAT; e += 512) {
        int r = e >> 7, c = e & 127;
        Wl[r * WSTR + c] = __float2half(W[e]);
    }
    const size_t base = (size_t)blockIdx.x * 64 * NFEAT;
    {
        const uint4* src = (const uint4*)(x2h + base);   // slack-allocated: safe overrun
        uint4* dst = (uint4*)&HT[0][0];
        dst[tid] = src[tid];
        dst[tid + 512] = src[tid + 512];
    }
    __syncthreads();

    unsigned int wreg[64];
    {
        const uint2* wr = (const uint2*)&Wl[lane * WSTR];
        #pragma unroll
        for (int t = 0; t < 32; ++t) {
            uint2 v = wr[t];
            wreg[2 * t] = v.x; wreg[2 * t + 1] = v.y;
        }
    }
    const float breg = b[lane];

    #pragma unroll 1
    for (int r = 0; r < 8; ++r) {
        int node = blockIdx.x * 64 + w * 8 + r;
        if (node >= N) break;
        const unsigned int* hrow = (const unsigned int*)&HT[w * 8 + r][0];
        float dot = breg;
        #pragma unroll
        for (int t = 0; t < 64; ++t)
            dot = dot2acc(hrow[t], wreg[t], dot);

        float m = dot;
        for (int o = 32; o > 0; o >>= 1) m = fmaxf(m, __shfl_xor(m, o));
        float ex = __expf(dot - m);
        float se = ex;
        for (int o = 32; o > 0; o >>= 1) se += __shfl_xor(se, o);
        out[(size_t)node * NCLS + lane] = dot - m - logf(se);
    }
}

// ---------- launch ----------

static inline size_t align256(size_t v) { return (v + 255) & ~(size_t)255; }

extern "C" void kernel_launch(void* const* d_in, const int* in_sizes, int n_in,
                              void* d_out, int out_size, void* d_ws, size_t ws_size,
                              hipStream_t stream) {
    const float* x  = (const float*)d_in[0];
    const int*   ei = (const int*)d_in[1];
    const float* W  = (const float*)d_in[2];
    const float* b  = (const float*)d_in[3];
    float* out = (float*)d_out;

    const int N = in_sizes[0] / NFEAT;   // 50000
    const int E = in_sizes[1] / 2;       // 800000
    const int* src = ei;
    const int* dst = ei + E;
    const int NB = (N + 255) / 256;      // 196 (= bucket count, dst>>8)
    const int NBUCK = NB;

    const int CSR_CAP = E + 7 * N + 64;  // rows padded to x8

    char* ws = (char*)d_ws;
    size_t o = 0;
    int*    cnt     = (int*)(ws + o);    o += align256((size_t)N * 4);
    float*  dinv    = (float*)(ws + o);  o += align256((size_t)N * 4);
    int*    row_ptr = (int*)(ws + o);    o += align256((size_t)(N + 1) * 4);
    int*    cursor  = (int*)(ws + o);    o += align256((size_t)N * 4);
    int*    bsums   = (int*)(ws + o);    o += align256(256 * 4);
    int*    h       = (int*)(ws + o);    o += align256((size_t)NBLK * 256 * 4);
    int*    btot    = (int*)(ws + o);    o += align256(256 * 4);
    int*    bbase   = (int*)(ws + o);    o += align256(257 * 4);
    int*    bsrc    = (int*)(ws + o);    o += align256((size_t)E * 4);
    int*    bdst    = (int*)(ws + o);    o += align256((size_t)E * 4);
    int*    csr     = (int*)(ws + o);    o += align256((size_t)CSR_CAP * 4);
    uint4*  xq      = (uint4*)(ws + o);  o += align256((size_t)(N + 1) * 128);  // fp8 rows
    uint4*  y1q     = (uint4*)(ws + o);  o += align256((size_t)(N + 1) * 128);  // fp8 rows
    __half* x2h     = (__half*)(ws + o); o += align256((size_t)(N + 64) * NFEAT * 2);

    const int E4 = (E + 3) / 4;
    const int F4 = (CSR_CAP + 3) / 4;

    hipMemsetAsync(cnt, 0, (size_t)N * 4, stream);
    histcount_kernel<<<NBLK, 256, 0, stream>>>(dst, cnt, h, E4, E, NBUCK);
    scan_local<<<NB, 256, 0, stream>>>(cnt, row_ptr, bsums, N);
    scan_finalize<<<NB, 256, 0, stream>>>(cnt, bsums, row_ptr, cursor, dinv, N);
    bucket_colscan_kernel<<<NBUCK, 256, 0, stream>>>(h, btot);
    bucket_scan_kernel<<<1, 256, 0, stream>>>(btot, bbase, NBUCK);
    bucket_scatter_kernel<<<NBLK, 256, 0, stream>>>(src, dst, h, bbase, bsrc, bdst, E4, E, NBUCK);
    fill_kernel<<<(F4 + 255) / 256, 256, 0, stream>>>(csr, N, F4);
    drain_kernel<<<NBUCK, 256, 0, stream>>>(bsrc, bdst, bbase, cursor, csr);
    prep_kernel<<<(N * RQ8 + RQ8 + 255) / 256, 256, 0, stream>>>(x, dinv, xq, y1q, N);
    hop_kernel<1, 0><<<(N + 3) / 4, 256, 0, stream>>>(xq, dinv, row_ptr, csr, y1q, N);
    hop_kernel<0, 1><<<(N + 3) / 4, 256, 0, stream>>>(y1q, dinv, row_ptr, csr, x2h, N);
    cls_kernel<<<(N + 63) / 64, 512, 0, stream>>>(x2h, W, b, out, N);
}